// Round 4
// baseline (855.008 us; speedup 1.0000x reference)
//
#include <hip/hip_runtime.h>
#include <math.h>

#define NN 2048
#define BATCH 32
#define COLS 64            // 32 sin cols + 32 cos cols
#define DT_STEP 0.1f
#define NSTEPS 10
#define JS 32              // j-splits
#define JR (NN / JS)       // 64
#define RB 32              // row blocks of 64 rows
#define GRID_SZ (JS * RB)  // 1024 blocks = 4 blocks/CU

// ---------------------------------------------------------------------------
// init: theta copy, X0[j][col] = {sin,cos}, zero split-K counters
// ---------------------------------------------------------------------------
__global__ __launch_bounds__(256) void init_kernel(const float* __restrict__ theta_in,
                                                   float* __restrict__ theta,
                                                   float* __restrict__ X0,
                                                   int* __restrict__ counters) {
    int t = blockIdx.x * 256 + threadIdx.x;
    int b = t >> 11;
    int i = t & (NN - 1);
    float th = theta_in[t];
    theta[t] = th;
    X0[(size_t)i * COLS + b]      = sinf(th);
    X0[(size_t)i * COLS + 32 + b] = cosf(th);
    if (t < NSTEPS * RB) counters[t] = 0;
}

#define FMA4(A, S, V)                      \
    A.x = fmaf(S, V.x, A.x);               \
    A.y = fmaf(S, V.y, A.y);               \
    A.z = fmaf(S, V.z, A.z);               \
    A.w = fmaf(S, V.w, A.w);

// ---------------------------------------------------------------------------
// step kernel: split-K GEMM (P[s][c][i] = sum_{j in s} K[i][j]*Xin[j][c])
// + last-block-per-rowblock fused Kuramoto update.
// block (s, rb): 64 rows x 64 cols, thread 4x4, double-buffered loads.
// ---------------------------------------------------------------------------
__global__ __launch_bounds__(256, 4) void step_kernel(const float* __restrict__ K,
                                                      const float* __restrict__ Xin,
                                                      float* __restrict__ Xout,
                                                      float* __restrict__ P,
                                                      float* __restrict__ theta,
                                                      const float* __restrict__ omega,
                                                      const float* __restrict__ Kg,
                                                      const float* __restrict__ mu,
                                                      int* __restrict__ counter) {
    __shared__ float lds[64][65];   // +1 pad: transpose read = 2 lanes/bank (free)
    __shared__ int isLast;

    const int bid = blockIdx.x;
    const int tid = threadIdx.x;
    const int s  = bid >> 5;
    const int rb = bid & 31;
    const int cg = tid & 15;
    const int rg = tid >> 4;
    const int c0 = cg * 4;
    const int rowBase = rb * 64 + rg * 4;
    const int j0 = s * JR;

    const float* Kp = K + (size_t)rowBase * NN + j0;
    const float* Xp = Xin + (size_t)j0 * COLS + c0;

#define LD4X(jj) (*(const float4*)(Xp + (size_t)(jj) * COLS))
#define LD4K(r, jj) (*(const float4*)(Kp + (size_t)(r) * NN + (jj)))

    float4 acc0 = {0.f,0.f,0.f,0.f}, acc1 = {0.f,0.f,0.f,0.f};
    float4 acc2 = {0.f,0.f,0.f,0.f}, acc3 = {0.f,0.f,0.f,0.f};

    float4 x0 = LD4X(0), x1 = LD4X(1), x2 = LD4X(2), x3 = LD4X(3);
    float4 k0 = LD4K(0,0), k1 = LD4K(1,0), k2 = LD4K(2,0), k3 = LD4K(3,0);

#pragma unroll 2
    for (int j = 0; j < JR; j += 4) {
        const int jn = j + ((j + 4 < JR) ? 4 : 0);   // last iter reloads self
        float4 nx0 = LD4X(jn + 0), nx1 = LD4X(jn + 1);
        float4 nx2 = LD4X(jn + 2), nx3 = LD4X(jn + 3);
        float4 nk0 = LD4K(0, jn), nk1 = LD4K(1, jn);
        float4 nk2 = LD4K(2, jn), nk3 = LD4K(3, jn);

        FMA4(acc0, k0.x, x0) FMA4(acc0, k0.y, x1) FMA4(acc0, k0.z, x2) FMA4(acc0, k0.w, x3)
        FMA4(acc1, k1.x, x0) FMA4(acc1, k1.y, x1) FMA4(acc1, k1.z, x2) FMA4(acc1, k1.w, x3)
        FMA4(acc2, k2.x, x0) FMA4(acc2, k2.y, x1) FMA4(acc2, k2.z, x2) FMA4(acc2, k2.w, x3)
        FMA4(acc3, k3.x, x0) FMA4(acc3, k3.y, x1) FMA4(acc3, k3.z, x2) FMA4(acc3, k3.w, x3)

        x0 = nx0; x1 = nx1; x2 = nx2; x3 = nx3;
        k0 = nk0; k1 = nk1; k2 = nk2; k3 = nk3;
    }
#undef LD4X
#undef LD4K

    // transposed (coalesced) P store via padded LDS
    const int lr = rg * 4;
    *(float4*)&lds[lr + 0][c0] = acc0;
    *(float4*)&lds[lr + 1][c0] = acc1;
    *(float4*)&lds[lr + 2][c0] = acc2;
    *(float4*)&lds[lr + 3][c0] = acc3;
    __syncthreads();

    const int io  = tid & 63;
    const int cg2 = tid >> 6;    // 0..3
    float* Pb = P + ((size_t)s * COLS + cg2 * 16) * NN + (size_t)rb * 64 + io;
#pragma unroll
    for (int cc = 0; cc < 16; ++cc)
        Pb[(size_t)cc * NN] = lds[io][cg2 * 16 + cc];

    // ---- split-K completion: last block for this row-block does the update
    __syncthreads();                       // drains vmcnt: all P stores in L2
    if (tid == 0) {
        __threadfence();                   // release: write back to coherent point
        int old = atomicAdd(counter + rb, 1);
        isLast = (old == JS - 1) ? 1 : 0;
    }
    __syncthreads();
    if (!isLast) return;
    __threadfence();                       // acquire: invalidate stale L1/L2

    // update rows rb*64..+63, all 32 batches: 2048 elems, 8 per thread
    const float g = (Kg[0] / (float)NN) * (mu[0] * 0.5f);
#pragma unroll
    for (int it = 0; it < 8; ++it) {
        int e  = it * 256 + tid;
        int il = e & 63;
        int b  = e >> 6;
        int i  = rb * 64 + il;

        float sumS = 0.f, sumC = 0.f;
#pragma unroll 8
        for (int ss = 0; ss < JS; ++ss) {
            sumS += P[((size_t)ss * COLS + b) * NN + i];
            sumC += P[((size_t)ss * COLS + 32 + b) * NN + i];
        }

        float th = theta[(size_t)b * NN + i];
        float sV = Xin[(size_t)i * COLS + b];
        float cV = Xin[(size_t)i * COLS + 32 + b];

        float dth = omega[i] + g * (cV * sumS - sV * sumC);
        float thn = th + DT_STEP * dth;
        float sn = sinf(thn);
        float cn = cosf(thn);
        theta[(size_t)b * NN + i] = atan2f(sn, cn);
        Xout[(size_t)i * COLS + b]      = sn;
        Xout[(size_t)i * COLS + 32 + b] = cn;
    }
}

// ---------------------------------------------------------------------------
// coherence
// ---------------------------------------------------------------------------
__global__ __launch_bounds__(256) void coh_kernel(const float* __restrict__ theta,
                                                  float* __restrict__ out) {
    int b = blockIdx.x;
    const float* th = theta + (size_t)b * NN;
    float sc = 0.f, ss = 0.f;
    for (int i = threadIdx.x; i < NN; i += 256) {
        float t = th[i];
        sc += cosf(t);
        ss += sinf(t);
    }
    for (int off = 32; off > 0; off >>= 1) {
        sc += __shfl_down(sc, off);
        ss += __shfl_down(ss, off);
    }
    __shared__ float red[2][4];
    int wave = threadIdx.x >> 6;
    if ((threadIdx.x & 63) == 0) { red[0][wave] = sc; red[1][wave] = ss; }
    __syncthreads();
    if (threadIdx.x == 0) {
        float csum = red[0][0] + red[0][1] + red[0][2] + red[0][3];
        float ssum = red[1][0] + red[1][1] + red[1][2] + red[1][3];
        float cm = csum / (float)NN;
        float sm = ssum / (float)NN;
        out[b] = sqrtf(cm * cm + sm * sm);
    }
}

extern "C" void kernel_launch(void* const* d_in, const int* in_sizes, int n_in,
                              void* d_out, int out_size, void* d_ws, size_t ws_size,
                              hipStream_t stream) {
    const float* theta0 = (const float*)d_in[0];
    const float* K      = (const float*)d_in[1];
    const float* omega  = (const float*)d_in[2];
    const float* Kg     = (const float*)d_in[3];
    const float* mu     = (const float*)d_in[4];

    float* out   = (float*)d_out;
    float* theta = out;                 // BATCH*NN
    float* coh   = out + BATCH * NN;    // BATCH

    float* X0 = (float*)d_ws;                          // NN x COLS (512 KB)
    float* X1 = X0 + (size_t)NN * COLS;                // NN x COLS (512 KB)
    float* P  = X1 + (size_t)NN * COLS;                // JS x COLS x NN (16 MB)
    int* counters = (int*)(P + (size_t)JS * COLS * NN);// NSTEPS x RB ints

    init_kernel<<<(BATCH * NN) / 256, 256, 0, stream>>>(theta0, theta, X0, counters);
    for (int step = 0; step < NSTEPS; ++step) {
        const float* xin = (step & 1) ? X1 : X0;
        float*       xout = (step & 1) ? X0 : X1;
        step_kernel<<<GRID_SZ, 256, 0, stream>>>(K, xin, xout, P, theta, omega,
                                                 Kg, mu, counters + step * RB);
    }
    coh_kernel<<<BATCH, 256, 0, stream>>>(theta, coh);
}

// Round 5
// 281.728 us; speedup vs baseline: 3.0349x; 3.0349x over previous
//
#include <hip/hip_runtime.h>
#include <math.h>

#define NN 2048
#define BATCH 32
#define COLS 64            // 32 sin cols + 32 cos cols
#define DT_STEP 0.1f
#define NSTEPS 10
#define JS 32              // j-splits
#define JR 64              // NN/JS
#define RB 32              // row blocks of 64 rows
#define GRID_SZ (JS * RB)  // 1024 blocks = 4 blocks/CU
#define NG (JR / 8)        // 8 j-groups of 8

// ---------------------------------------------------------------------------
// init: theta copy + X[j][col]: X[j][b]=sin, X[j][32+b]=cos
// ---------------------------------------------------------------------------
__global__ __launch_bounds__(256) void init_kernel(const float* __restrict__ theta_in,
                                                   float* __restrict__ theta,
                                                   float* __restrict__ X) {
    int t = blockIdx.x * 256 + threadIdx.x;
    int b = t >> 11;
    int i = t & (NN - 1);
    float th = theta_in[t];
    theta[t] = th;
    X[(size_t)i * COLS + b]      = sinf(th);
    X[(size_t)i * COLS + 32 + b] = cosf(th);
}

#define FMA4(A, S, V)                      \
    A.x = fmaf(S, V.x, A.x);               \
    A.y = fmaf(S, V.y, A.y);               \
    A.z = fmaf(S, V.z, A.z);               \
    A.w = fmaf(S, V.w, A.w);

// ---------------------------------------------------------------------------
// GEMM: P[s][c][i] = sum_{j in split s} K[i][j] * X[j][c]
// block (s,rb): 64 rows x 64 cols; X-slab staged in LDS; K streamed through
// an explicit 2-stage register pipeline (8 float4 in flight per thread).
// NOTE: plain __launch_bounds__(256) — round 4 showed (256,4) collapses
// VGPRs to 32 and serializes every load (86us/step at 6% VALU).
// ---------------------------------------------------------------------------
__global__ __launch_bounds__(256) void gemm_step_kernel(const float* __restrict__ K,
                                                        const float* __restrict__ X,
                                                        float* __restrict__ P) {
    __shared__ float Xs[JR][COLS];   // 16 KB staged X-slab
    __shared__ float T[64][65];      // padded transpose buffer for P store

    const int tid = threadIdx.x;
    const int bid = blockIdx.x;
    const int s  = bid >> 5;
    const int rb = bid & 31;
    const int cg = tid & 15;
    const int rg = tid >> 4;
    const int c0 = cg * 4;
    const int rowBase = rb * 64 + rg * 4;
    const int j0 = s * JR;

    // ---- stage X slab: 4096 floats = 1024 float4, coalesced, independent
    {
        const float4* Xg = (const float4*)(X + (size_t)j0 * COLS);
        float4* Xl = (float4*)&Xs[0][0];
#pragma unroll
        for (int u = 0; u < 4; ++u)
            Xl[u * 256 + tid] = Xg[u * 256 + tid];
    }
    __syncthreads();

    const float* Kp = K + (size_t)rowBase * NN + j0;

    float4 acc0 = {0.f,0.f,0.f,0.f}, acc1 = {0.f,0.f,0.f,0.f};
    float4 acc2 = {0.f,0.f,0.f,0.f}, acc3 = {0.f,0.f,0.f,0.f};

    // 2-stage pipelined K stream: per 8-j group load 2 quads x 4 rows
    float4 ka[8], kb[8];

#define LOADK(BUF, JB)                                                   \
    BUF[0] = *(const float4*)(Kp + 0 * NN + (JB));                       \
    BUF[1] = *(const float4*)(Kp + 0 * NN + (JB) + 4);                   \
    BUF[2] = *(const float4*)(Kp + 1 * NN + (JB));                       \
    BUF[3] = *(const float4*)(Kp + 1 * NN + (JB) + 4);                   \
    BUF[4] = *(const float4*)(Kp + 2 * NN + (JB));                       \
    BUF[5] = *(const float4*)(Kp + 2 * NN + (JB) + 4);                   \
    BUF[6] = *(const float4*)(Kp + 3 * NN + (JB));                       \
    BUF[7] = *(const float4*)(Kp + 3 * NN + (JB) + 4);

#define COMPUTE(BUF, JB)                                                 \
    _Pragma("unroll")                                                    \
    for (int q = 0; q < 2; ++q) {                                        \
        const int jj = (JB) + q * 4;                                     \
        float4 xv0 = *(const float4*)&Xs[jj + 0][c0];                    \
        float4 xv1 = *(const float4*)&Xs[jj + 1][c0];                    \
        float4 xv2 = *(const float4*)&Xs[jj + 2][c0];                    \
        float4 xv3 = *(const float4*)&Xs[jj + 3][c0];                    \
        FMA4(acc0, BUF[0 + q].x, xv0) FMA4(acc0, BUF[0 + q].y, xv1)      \
        FMA4(acc0, BUF[0 + q].z, xv2) FMA4(acc0, BUF[0 + q].w, xv3)      \
        FMA4(acc1, BUF[2 + q].x, xv0) FMA4(acc1, BUF[2 + q].y, xv1)      \
        FMA4(acc1, BUF[2 + q].z, xv2) FMA4(acc1, BUF[2 + q].w, xv3)      \
        FMA4(acc2, BUF[4 + q].x, xv0) FMA4(acc2, BUF[4 + q].y, xv1)      \
        FMA4(acc2, BUF[4 + q].z, xv2) FMA4(acc2, BUF[4 + q].w, xv3)      \
        FMA4(acc3, BUF[6 + q].x, xv0) FMA4(acc3, BUF[6 + q].y, xv1)      \
        FMA4(acc3, BUF[6 + q].z, xv2) FMA4(acc3, BUF[6 + q].w, xv3)      \
    }

    LOADK(ka, 0)
#pragma unroll
    for (int g = 0; g < NG - 1; ++g) {
        if ((g & 1) == 0) { LOADK(kb, (g + 1) * 8) COMPUTE(ka, g * 8) }
        else              { LOADK(ka, (g + 1) * 8) COMPUTE(kb, g * 8) }
    }
    COMPUTE(kb, (NG - 1) * 8)   // NG-1 = 7 is odd: last-loaded buffer is kb

#undef LOADK
#undef COMPUTE

    // ---- transposed (coalesced) P store via padded LDS
    __syncthreads();   // Xs reads done before T overwrites nothing (separate), but
                       // keep ordering vs staging reuse across waves
    const int lr = rg * 4;
    *(float4*)&T[lr + 0][c0] = acc0;
    *(float4*)&T[lr + 1][c0] = acc1;
    *(float4*)&T[lr + 2][c0] = acc2;
    *(float4*)&T[lr + 3][c0] = acc3;
    __syncthreads();

    const int io  = tid & 63;
    const int cg2 = tid >> 6;    // 0..3
    float* Pb = P + ((size_t)s * COLS + cg2 * 16) * NN + (size_t)rb * 64 + io;
#pragma unroll
    for (int cc = 0; cc < 16; ++cc)
        Pb[(size_t)cc * NN] = T[io][cg2 * 16 + cc];
}

// ---------------------------------------------------------------------------
// update: coalesced P reads (4 independent accumulator chains), Kuramoto
// step, wrap, refresh X in place. t = b*NN + i
// ---------------------------------------------------------------------------
__global__ __launch_bounds__(256) void update_step_kernel(float* __restrict__ theta,
                                                          float* __restrict__ X,
                                                          const float* __restrict__ P,
                                                          const float* __restrict__ omega,
                                                          const float* __restrict__ Kg,
                                                          const float* __restrict__ mu) {
    int t = blockIdx.x * 256 + threadIdx.x;
    int b = t >> 11;
    int i = t & (NN - 1);

    float sA = 0.f, sB = 0.f, cA = 0.f, cB = 0.f;
#pragma unroll
    for (int ss = 0; ss < JS; ss += 2) {
        sA += P[((size_t)(ss + 0) * COLS + b) * NN + i];
        sB += P[((size_t)(ss + 1) * COLS + b) * NN + i];
        cA += P[((size_t)(ss + 0) * COLS + 32 + b) * NN + i];
        cB += P[((size_t)(ss + 1) * COLS + 32 + b) * NN + i];
    }
    float sumS = sA + sB;
    float sumC = cA + cB;

    float g = (Kg[0] / (float)NN) * (mu[0] * 0.5f);
    float th = theta[t];
    float sV = X[(size_t)i * COLS + b];
    float cV = X[(size_t)i * COLS + 32 + b];

    float dth = omega[i] + g * (cV * sumS - sV * sumC);
    float thn = th + DT_STEP * dth;
    float sn = sinf(thn);
    float cn = cosf(thn);
    theta[t] = atan2f(sn, cn);
    X[(size_t)i * COLS + b]      = sn;
    X[(size_t)i * COLS + 32 + b] = cn;
}

// ---------------------------------------------------------------------------
// coherence
// ---------------------------------------------------------------------------
__global__ __launch_bounds__(256) void coh_kernel(const float* __restrict__ theta,
                                                  float* __restrict__ out) {
    int b = blockIdx.x;
    const float* th = theta + (size_t)b * NN;
    float sc = 0.f, ss = 0.f;
    for (int i = threadIdx.x; i < NN; i += 256) {
        float t = th[i];
        sc += cosf(t);
        ss += sinf(t);
    }
    for (int off = 32; off > 0; off >>= 1) {
        sc += __shfl_down(sc, off);
        ss += __shfl_down(ss, off);
    }
    __shared__ float red[2][4];
    int wave = threadIdx.x >> 6;
    if ((threadIdx.x & 63) == 0) { red[0][wave] = sc; red[1][wave] = ss; }
    __syncthreads();
    if (threadIdx.x == 0) {
        float csum = red[0][0] + red[0][1] + red[0][2] + red[0][3];
        float ssum = red[1][0] + red[1][1] + red[1][2] + red[1][3];
        float cm = csum / (float)NN;
        float sm = ssum / (float)NN;
        out[b] = sqrtf(cm * cm + sm * sm);
    }
}

extern "C" void kernel_launch(void* const* d_in, const int* in_sizes, int n_in,
                              void* d_out, int out_size, void* d_ws, size_t ws_size,
                              hipStream_t stream) {
    const float* theta0 = (const float*)d_in[0];
    const float* K      = (const float*)d_in[1];
    const float* omega  = (const float*)d_in[2];
    const float* Kg     = (const float*)d_in[3];
    const float* mu     = (const float*)d_in[4];

    float* out   = (float*)d_out;
    float* theta = out;                 // BATCH*NN
    float* coh   = out + BATCH * NN;    // BATCH

    float* X = (float*)d_ws;                       // NN x COLS      (512 KB)
    float* P = X + (size_t)NN * COLS;              // JS x COLS x NN (16.8 MB)

    init_kernel<<<(BATCH * NN) / 256, 256, 0, stream>>>(theta0, theta, X);
    for (int step = 0; step < NSTEPS; ++step) {
        gemm_step_kernel<<<GRID_SZ, 256, 0, stream>>>(K, X, P);
        update_step_kernel<<<(BATCH * NN) / 256, 256, 0, stream>>>(theta, X, P, omega, Kg, mu);
    }
    coh_kernel<<<BATCH, 256, 0, stream>>>(theta, coh);
}

// Round 6
// 253.804 us; speedup vs baseline: 3.3688x; 1.1100x over previous
//
#include <hip/hip_runtime.h>
#include <math.h>

#define NN 2048
#define BATCH 32
#define COLS 64            // 32 sin cols + 32 cos cols
#define DT_STEP 0.1f
#define NSTEPS 10
#define JS 16              // j-splits
#define JR 128             // NN/JS
#define RB 32              // row blocks of 64 rows
#define GRID_SZ (JS * RB)  // 512 blocks = 2 blocks/CU

// ---------------------------------------------------------------------------
// async global->LDS (16B/lane/instr). LDS dest must be WAVE-UNIFORM base;
// HW writes base + lane*16. Global src is per-lane. [guide m03/m97/m104]
// ---------------------------------------------------------------------------
#if defined(__has_builtin)
#if __has_builtin(__builtin_amdgcn_global_load_lds)
#define HAVE_GLOBAL_LOAD_LDS 1
#endif
#endif

__device__ __forceinline__ void async_copy16(const float* g, float* l) {
#ifdef HAVE_GLOBAL_LOAD_LDS
    __builtin_amdgcn_global_load_lds(
        (const __attribute__((address_space(1))) void*)g,
        (__attribute__((address_space(3))) void*)l, 16, 0, 0);
#else
    // fallback: reg-staged (per-lane addr math mirrors HW semantics)
    int lane = threadIdx.x & 63;
    *(float4*)(l + lane * 4) = *(const float4*)(g);
#endif
}

// ---------------------------------------------------------------------------
// init: theta copy + X[j][col]: X[j][b]=sin, X[j][32+b]=cos
// ---------------------------------------------------------------------------
__global__ __launch_bounds__(256) void init_kernel(const float* __restrict__ theta_in,
                                                   float* __restrict__ theta,
                                                   float* __restrict__ X) {
    int t = blockIdx.x * 256 + threadIdx.x;
    int b = t >> 11;
    int i = t & (NN - 1);
    float th = theta_in[t];
    theta[t] = th;
    X[(size_t)i * COLS + b]      = sinf(th);
    X[(size_t)i * COLS + 32 + b] = cosf(th);
}

#define FMA4(A, S, V)                      \
    A.x = fmaf(S, V.x, A.x);               \
    A.y = fmaf(S, V.y, A.y);               \
    A.z = fmaf(S, V.z, A.z);               \
    A.w = fmaf(S, V.w, A.w);

// ---------------------------------------------------------------------------
// GEMM: P[s][c][i] = sum_{j in split s} K[i][j] * X[j][c]
// block (s,rb): 64 rows x 64 cols x K-slice 128. K-tile AND X-slab staged
// into LDS via async global_load_lds (deep queue -> latency paid once).
// Compute reads LDS only. Transpose buffer overlays K-tile after barrier.
// NOTE: plain __launch_bounds__(256) — (256,4) collapsed VGPRs to 32 in r4.
// ---------------------------------------------------------------------------
__global__ __launch_bounds__(256) void gemm_step_kernel(const float* __restrict__ K,
                                                        const float* __restrict__ X,
                                                        float* __restrict__ P) {
    __shared__ float smem[16384];            // 64 KB
    float* Klds = smem;                      // [64][128] = 32 KB
    float* Xs   = smem + 8192;               // [128][64] = 32 KB

    const int tid = threadIdx.x;
    const int bid = blockIdx.x;
    const int s  = bid >> 5;
    const int rb = bid & 31;
    const int w  = tid >> 6;                 // wave 0..3
    const int ln = tid & 63;
    const int cg = tid & 15;
    const int rg = tid >> 4;                 // 0..15
    const int c0 = cg * 4;
    const int j0 = s * JR;

    // ---- async stage K-tile: 64 rows x 128 j. Per instr: 2 rows (1 KB).
    {
        const float* Kg = K + (size_t)rb * 64 * NN + j0;
        const int sub = ln >> 5;             // 0/1: which row of the pair
        const int col4 = (ln & 31) * 4;      // 0..124
#pragma unroll
        for (int u = 0; u < 8; ++u) {
            const int r0 = u * 8 + w * 2;    // wave-uniform row pair base
            async_copy16(Kg + (size_t)(r0 + sub) * NN + col4,
                         Klds + r0 * JR);
        }
    }
    // ---- async stage X-slab: 128 j x 64 c, contiguous 32 KB.
    {
        const float* Xg = X + (size_t)j0 * COLS;
#pragma unroll
        for (int u = 0; u < 8; ++u) {
            const int base = u * 1024 + w * 256;   // wave-uniform
            async_copy16(Xg + base + ln * 4, Xs + base);
        }
    }
    __syncthreads();   // drains vmcnt(0): all staged data visible

    // ---- compute from LDS: 4x4 thread tile over 128 j
    const float* KpL = Klds + (size_t)(rg * 4) * JR;

    float4 acc0 = {0.f,0.f,0.f,0.f}, acc1 = {0.f,0.f,0.f,0.f};
    float4 acc2 = {0.f,0.f,0.f,0.f}, acc3 = {0.f,0.f,0.f,0.f};

#pragma unroll 8
    for (int j = 0; j < JR; j += 4) {
        float4 xv0 = *(const float4*)(Xs + (size_t)(j + 0) * COLS + c0);
        float4 xv1 = *(const float4*)(Xs + (size_t)(j + 1) * COLS + c0);
        float4 xv2 = *(const float4*)(Xs + (size_t)(j + 2) * COLS + c0);
        float4 xv3 = *(const float4*)(Xs + (size_t)(j + 3) * COLS + c0);
        float4 k0 = *(const float4*)(KpL + 0 * JR + j);
        float4 k1 = *(const float4*)(KpL + 1 * JR + j);
        float4 k2 = *(const float4*)(KpL + 2 * JR + j);
        float4 k3 = *(const float4*)(KpL + 3 * JR + j);

        FMA4(acc0, k0.x, xv0) FMA4(acc0, k0.y, xv1) FMA4(acc0, k0.z, xv2) FMA4(acc0, k0.w, xv3)
        FMA4(acc1, k1.x, xv0) FMA4(acc1, k1.y, xv1) FMA4(acc1, k1.z, xv2) FMA4(acc1, k1.w, xv3)
        FMA4(acc2, k2.x, xv0) FMA4(acc2, k2.y, xv1) FMA4(acc2, k2.z, xv2) FMA4(acc2, k2.w, xv3)
        FMA4(acc3, k3.x, xv0) FMA4(acc3, k3.y, xv1) FMA4(acc3, k3.z, xv2) FMA4(acc3, k3.w, xv3)
    }

    // ---- transposed (coalesced) P store; T overlays the K-tile region
    __syncthreads();                         // all waves done reading Klds/Xs
    float (*T)[65] = (float (*)[65])smem;    // 64x65 = 16.6 KB, fits in 32 KB
    const int lr = rg * 4;
    *(float4*)&T[lr + 0][c0] = acc0;
    *(float4*)&T[lr + 1][c0] = acc1;
    *(float4*)&T[lr + 2][c0] = acc2;
    *(float4*)&T[lr + 3][c0] = acc3;
    __syncthreads();

    const int io  = tid & 63;
    const int cg2 = tid >> 6;                // 0..3
    float* Pb = P + ((size_t)s * COLS + cg2 * 16) * NN + (size_t)rb * 64 + io;
#pragma unroll
    for (int cc = 0; cc < 16; ++cc)
        Pb[(size_t)cc * NN] = T[io][cg2 * 16 + cc];
}

// ---------------------------------------------------------------------------
// update: coalesced P reads (4 accumulator chains), Kuramoto step, wrap,
// refresh X in place. t = b*NN + i
// ---------------------------------------------------------------------------
__global__ __launch_bounds__(256) void update_step_kernel(float* __restrict__ theta,
                                                          float* __restrict__ X,
                                                          const float* __restrict__ P,
                                                          const float* __restrict__ omega,
                                                          const float* __restrict__ Kg,
                                                          const float* __restrict__ mu) {
    int t = blockIdx.x * 256 + threadIdx.x;
    int b = t >> 11;
    int i = t & (NN - 1);

    float sA = 0.f, sB = 0.f, cA = 0.f, cB = 0.f;
#pragma unroll
    for (int ss = 0; ss < JS; ss += 2) {
        sA += P[((size_t)(ss + 0) * COLS + b) * NN + i];
        sB += P[((size_t)(ss + 1) * COLS + b) * NN + i];
        cA += P[((size_t)(ss + 0) * COLS + 32 + b) * NN + i];
        cB += P[((size_t)(ss + 1) * COLS + 32 + b) * NN + i];
    }
    float sumS = sA + sB;
    float sumC = cA + cB;

    float g = (Kg[0] / (float)NN) * (mu[0] * 0.5f);
    float th = theta[t];
    float sV = X[(size_t)i * COLS + b];
    float cV = X[(size_t)i * COLS + 32 + b];

    float dth = omega[i] + g * (cV * sumS - sV * sumC);
    float thn = th + DT_STEP * dth;
    float sn = sinf(thn);
    float cn = cosf(thn);
    theta[t] = atan2f(sn, cn);
    X[(size_t)i * COLS + b]      = sn;
    X[(size_t)i * COLS + 32 + b] = cn;
}

// ---------------------------------------------------------------------------
// coherence
// ---------------------------------------------------------------------------
__global__ __launch_bounds__(256) void coh_kernel(const float* __restrict__ theta,
                                                  float* __restrict__ out) {
    int b = blockIdx.x;
    const float* th = theta + (size_t)b * NN;
    float sc = 0.f, ss = 0.f;
    for (int i = threadIdx.x; i < NN; i += 256) {
        float t = th[i];
        sc += cosf(t);
        ss += sinf(t);
    }
    for (int off = 32; off > 0; off >>= 1) {
        sc += __shfl_down(sc, off);
        ss += __shfl_down(ss, off);
    }
    __shared__ float red[2][4];
    int wave = threadIdx.x >> 6;
    if ((threadIdx.x & 63) == 0) { red[0][wave] = sc; red[1][wave] = ss; }
    __syncthreads();
    if (threadIdx.x == 0) {
        float csum = red[0][0] + red[0][1] + red[0][2] + red[0][3];
        float ssum = red[1][0] + red[1][1] + red[1][2] + red[1][3];
        float cm = csum / (float)NN;
        float sm = ssum / (float)NN;
        out[b] = sqrtf(cm * cm + sm * sm);
    }
}

extern "C" void kernel_launch(void* const* d_in, const int* in_sizes, int n_in,
                              void* d_out, int out_size, void* d_ws, size_t ws_size,
                              hipStream_t stream) {
    const float* theta0 = (const float*)d_in[0];
    const float* K      = (const float*)d_in[1];
    const float* omega  = (const float*)d_in[2];
    const float* Kg     = (const float*)d_in[3];
    const float* mu     = (const float*)d_in[4];

    float* out   = (float*)d_out;
    float* theta = out;                 // BATCH*NN
    float* coh   = out + BATCH * NN;    // BATCH

    float* X = (float*)d_ws;                       // NN x COLS      (512 KB)
    float* P = X + (size_t)NN * COLS;              // JS x COLS x NN (8.4 MB)

    init_kernel<<<(BATCH * NN) / 256, 256, 0, stream>>>(theta0, theta, X);
    for (int step = 0; step < NSTEPS; ++step) {
        gemm_step_kernel<<<GRID_SZ, 256, 0, stream>>>(K, X, P);
        update_step_kernel<<<(BATCH * NN) / 256, 256, 0, stream>>>(theta, X, P, omega, Kg, mu);
    }
    coh_kernel<<<BATCH, 256, 0, stream>>>(theta, coh);
}